// Round 1
// baseline (214.791 us; speedup 1.0000x reference)
//
#include <hip/hip_runtime.h>

typedef __attribute__((ext_vector_type(8))) short short8;   // 8 bf16 (4 VGPRs)
typedef __attribute__((ext_vector_type(4))) float floatx4;  // MFMA C/D

// (B,T,D) = (128,1024,64) fp32. out[i][j][t] = prod_{s<=t}(1 + <dX(s-1),dY(s-1)>/dt)
constexpr int BX    = 128;
constexpr int TT    = 1024;
constexpr int DDIM  = 64;
constexpr int NPAIR = BX * BX;
constexpr int LCH   = 16;              // t-steps per block; out flushes are 32B sectors
constexpr int NCH   = TT / LCH;        // 64
constexpr float DT_INV = 1023.0f;

// LDS element index for bf16 rows of 64 with XOR-segment swizzle (16B segments).
// Balanced: every frag read/staging write lands 8 lanes per bank-quad (BW floor).
__device__ __forceinline__ int sidxE(int row, int k) {
    return row * 64 + ((((k >> 3) ^ (row & 7)) << 3) | (k & 7));
}

__device__ __forceinline__ ushort f2bf(float f) {           // round-to-nearest-even bf16
    uint u = __builtin_bit_cast(uint, f);
    u += 0x7fffu + ((u >> 16) & 1u);
    return (ushort)(u >> 16);
}

// 8 floats -> hi/lo bf16 split, two 16B LDS stores.
__device__ __forceinline__ void cvt_store(ushort* hiP, ushort* loP, const float* v) {
    uint hw[4], lw[4];
#pragma unroll
    for (int p = 0; p < 4; ++p) {
        const ushort h0 = f2bf(v[2 * p]), h1 = f2bf(v[2 * p + 1]);
        const float r0 = v[2 * p]     - __builtin_bit_cast(float, (uint)h0 << 16);
        const float r1 = v[2 * p + 1] - __builtin_bit_cast(float, (uint)h1 << 16);
        const ushort l0 = f2bf(r0), l1 = f2bf(r1);
        hw[p] = (uint)h0 | ((uint)h1 << 16);
        lw[p] = (uint)l0 | ((uint)l1 << 16);
    }
    *(uint4*)hiP = make_uint4(hw[0], hw[1], hw[2], hw[3]);
    *(uint4*)loP = make_uint4(lw[0], lw[1], lw[2], lw[3]);
}

__device__ __forceinline__ void ld8(const float* p, float* dst) {
    const float4 a = *(const float4*)p;
    const float4 b = *(const float4*)(p + 4);
    dst[0] = a.x; dst[1] = a.y; dst[2] = a.z; dst[3] = a.w;
    dst[4] = b.x; dst[5] = b.y; dst[6] = b.z; dst[7] = b.w;
}

// Kernel A: 64i x 32j pair tile x 16 t-steps. Split-bf16 3-term MFMA dots.
// grid (2,4,64)=512 blocks (2/CU), 256 thr = 4 waves; wave w: rows w*16..+15, 2 n-subtiles.
__global__ __launch_bounds__(256, 2) void zchunk_kernel(const float* __restrict__ X,
                                                        const float* __restrict__ Y,
                                                        float* __restrict__ out,
                                                        float* __restrict__ P)
{
    __shared__ __align__(16) ushort smXhi[2][64 * 64], smXlo[2][64 * 64];  // 32 KB
    __shared__ __align__(16) ushort smYhi[2][32 * 64], smYlo[2][32 * 64];  // 16 KB

    const int i0 = blockIdx.x * 64;
    const int j0 = blockIdx.y * 32;
    const int t0 = blockIdx.z * LCH;
    const int tid  = (int)threadIdx.x;
    const int lane = tid & 63, w = tid >> 6, quad = lane >> 4, l15 = lane & 15;

    // staging slots: X rows (tid>>3) and (tid>>3)+32; Y row (tid>>3); k-segment tid&7
    const int srow = tid >> 3;          // 0..31
    const int sseg = tid & 7;
    const float* xp0 = X + (size_t)(i0 + srow)      * TT * DDIM + sseg * 8;
    const float* xp1 = X + (size_t)(i0 + srow + 32) * TT * DDIM + sseg * 8;
    const float* yp  = Y + (size_t)(j0 + srow)      * TT * DDIM + sseg * 8;

    float cx0[8], cx1[8], cy[8];        // current slice values (fp32)
    {
        const int sa = (t0 == 0) ? 0 : (t0 - 1);
        float pv[8], d[8];
        ld8(xp0 + (size_t)t0 * DDIM, cx0);
        ld8(xp0 + (size_t)sa * DDIM, pv);
#pragma unroll
        for (int k = 0; k < 8; ++k) d[k] = cx0[k] - pv[k];
        cvt_store(&smXhi[0][sidxE(srow, sseg * 8)], &smXlo[0][sidxE(srow, sseg * 8)], d);

        ld8(xp1 + (size_t)t0 * DDIM, cx1);
        ld8(xp1 + (size_t)sa * DDIM, pv);
#pragma unroll
        for (int k = 0; k < 8; ++k) d[k] = cx1[k] - pv[k];
        cvt_store(&smXhi[0][sidxE(srow + 32, sseg * 8)], &smXlo[0][sidxE(srow + 32, sseg * 8)], d);

        ld8(yp + (size_t)t0 * DDIM, cy);
        ld8(yp + (size_t)sa * DDIM, pv);
#pragma unroll
        for (int k = 0; k < 8; ++k) d[k] = cy[k] - pv[k];
        cvt_store(&smYhi[0][sidxE(srow, sseg * 8)], &smYlo[0][sidxE(srow, sseg * 8)], d);
    }

    float cum[2][4];
    float hist[2][4][8];                // 8-step history -> 32B flushes
#pragma unroll
    for (int s = 0; s < 2; ++s)
#pragma unroll
        for (int r = 0; r < 4; ++r) cum[s][r] = 1.f;

    __syncthreads();

#pragma unroll
    for (int h = 0; h < LCH; ++h) {
        const int cur = h & 1;

        float nx0[8], nx1[8], ny[8];
        if (h + 1 < LCH) {              // prefetch next slice (global latency under MFMA)
            const size_t u = (size_t)(t0 + h + 1) * DDIM;
            ld8(xp0 + u, nx0); ld8(xp1 + u, nx1); ld8(yp + u, ny);
        }

        // A frags for this wave's 16-row strip (row = w*16 + l15, k = kk*32 + quad*8)
        short8 aHi[2], aLo[2];
#pragma unroll
        for (int kk = 0; kk < 2; ++kk) {
            const int e = sidxE(w * 16 + l15, kk * 32 + quad * 8);
            aHi[kk] = *(const short8*)&smXhi[cur][e];
            aLo[kk] = *(const short8*)&smXlo[cur][e];
        }

#pragma unroll
        for (int sub = 0; sub < 2; ++sub) {
            floatx4 acc = {0.f, 0.f, 0.f, 0.f};
#pragma unroll
            for (int kk = 0; kk < 2; ++kk) {
                const int e = sidxE(sub * 16 + l15, kk * 32 + quad * 8);
                const short8 bHi = *(const short8*)&smYhi[cur][e];
                const short8 bLo = *(const short8*)&smYlo[cur][e];
                acc = __builtin_amdgcn_mfma_f32_16x16x32_bf16(aLo[kk], bHi, acc, 0, 0, 0);
                acc = __builtin_amdgcn_mfma_f32_16x16x32_bf16(aHi[kk], bLo, acc, 0, 0, 0);
                acc = __builtin_amdgcn_mfma_f32_16x16x32_bf16(aHi[kk], bHi, acc, 0, 0, 0);
            }
#pragma unroll
            for (int r = 0; r < 4; ++r) {
                cum[sub][r] *= fmaf(acc[r], DT_INV, 1.f);
                hist[sub][r][h & 7] = cum[sub][r];
            }
        }

        if (h + 1 < LCH) {              // stage next step's diffs into other buffer
            float d[8];
#pragma unroll
            for (int k = 0; k < 8; ++k) d[k] = nx0[k] - cx0[k];
            cvt_store(&smXhi[cur ^ 1][sidxE(srow, sseg * 8)], &smXlo[cur ^ 1][sidxE(srow, sseg * 8)], d);
#pragma unroll
            for (int k = 0; k < 8; ++k) d[k] = nx1[k] - cx1[k];
            cvt_store(&smXhi[cur ^ 1][sidxE(srow + 32, sseg * 8)], &smXlo[cur ^ 1][sidxE(srow + 32, sseg * 8)], d);
#pragma unroll
            for (int k = 0; k < 8; ++k) d[k] = ny[k] - cy[k];
            cvt_store(&smYhi[cur ^ 1][sidxE(srow, sseg * 8)], &smYlo[cur ^ 1][sidxE(srow, sseg * 8)], d);
#pragma unroll
            for (int k = 0; k < 8; ++k) { cx0[k] = nx0[k]; cx1[k] = nx1[k]; cy[k] = ny[k]; }
            __syncthreads();
        }

        if ((h & 7) == 7) {             // 32B-aligned full-sector flush (NO sub-sector stores!)
            const int tb = t0 + h - 7;
#pragma unroll
            for (int sub = 0; sub < 2; ++sub)
#pragma unroll
                for (int r = 0; r < 4; ++r) {
                    float* o = out + (size_t)((i0 + w * 16 + quad * 4 + r) * BX +
                                              (j0 + sub * 16 + l15)) * TT + tb;
                    *(float4*)o       = make_float4(hist[sub][r][0], hist[sub][r][1],
                                                    hist[sub][r][2], hist[sub][r][3]);
                    *(float4*)(o + 4) = make_float4(hist[sub][r][4], hist[sub][r][5],
                                                    hist[sub][r][6], hist[sub][r][7]);
                }
        }
    }

    // chunk totals, [chunk][pair] (coalesced-ish scatter, 4 MB total)
#pragma unroll
    for (int sub = 0; sub < 2; ++sub)
#pragma unroll
        for (int r = 0; r < 4; ++r) {
            const int pair = (i0 + w * 16 + quad * 4 + r) * BX + (j0 + sub * 16 + l15);
            P[(size_t)blockIdx.z * NPAIR + pair] = cum[sub][r];
        }
}

// Kernel B: exclusive prefix product over chunks per pair ([chunk][pair], coalesced).
__global__ __launch_bounds__(256) void scan_kernel(float* __restrict__ P)
{
    const int p = blockIdx.x * 256 + (int)threadIdx.x;
    float run = 1.f;
#pragma unroll 4
    for (int c = 0; c < NCH; ++c) {
        const size_t idx = (size_t)c * NPAIR + p;
        const float v = P[idx];
        P[idx] = run;
        run *= v;
    }
}

// Kernel C: out[p][t] *= P[t/LCH][p] — coalesced float4 pass.
__global__ __launch_bounds__(256) void scale_kernel(float* __restrict__ out,
                                                    const float* __restrict__ P)
{
    const size_t g    = (size_t)blockIdx.x * 256 + threadIdx.x;
    const size_t base = g * 4;
    const int p = (int)(base >> 10);
    const int t = (int)(base & (TT - 1));
    const float f = P[(size_t)(t >> 4) * NPAIR + p];
    float4 v = *(float4*)(out + base);
    v.x *= f; v.y *= f; v.z *= f; v.w *= f;
    *(float4*)(out + base) = v;
}

extern "C" void kernel_launch(void* const* d_in, const int* in_sizes, int n_in,
                              void* d_out, int out_size, void* d_ws, size_t ws_size,
                              hipStream_t stream)
{
    const float* X = (const float*)d_in[0];
    const float* Y = (const float*)d_in[1];
    float* out = (float*)d_out;
    float* P   = (float*)d_ws;          // NCH*NPAIR*4 = 4 MB

    zchunk_kernel<<<dim3(2, 4, NCH), 256, 0, stream>>>(X, Y, out, P);
    scan_kernel<<<dim3(NPAIR / 256), 256, 0, stream>>>(P);
    scale_kernel<<<dim3((NPAIR * TT / 4) / 256), 256, 0, stream>>>(out, P);
}

// Round 3
// 187.109 us; speedup vs baseline: 1.1479x; 1.1479x over previous
//
#include <hip/hip_runtime.h>

typedef __attribute__((ext_vector_type(8))) short short8;   // 8 bf16 (4 VGPRs)
typedef __attribute__((ext_vector_type(4))) float floatx4;  // MFMA C/D

// (B,T,D) = (128,1024,64) fp32. out[i][j][t] = prod_{s<=t}(1 + <dX(s-1),dY(s-1)>/dt)
constexpr int BX    = 128;
constexpr int TT    = 1024;
constexpr int DDIM  = 64;
constexpr int NPAIR = BX * BX;
constexpr int LCH   = 16;              // t-steps per block
constexpr int NCH   = TT / LCH;        // 64
constexpr float DT_INV = 1023.0f;

// LDS element index for bf16 rows of 64 with XOR-segment swizzle (16B segments).
__device__ __forceinline__ int sidxE(int row, int k) {
    return row * 64 + ((((k >> 3) ^ (row & 7)) << 3) | (k & 7));
}

__device__ __forceinline__ ushort f2bf(float f) {           // round-to-nearest-even bf16
    uint u = __builtin_bit_cast(uint, f);
    u += 0x7fffu + ((u >> 16) & 1u);
    return (ushort)(u >> 16);
}

// 8 floats -> hi/lo bf16 split, two 16B LDS stores.
__device__ __forceinline__ void cvt_store(ushort* hiP, ushort* loP, const float* v) {
    uint hw[4], lw[4];
#pragma unroll
    for (int p = 0; p < 4; ++p) {
        const ushort h0 = f2bf(v[2 * p]), h1 = f2bf(v[2 * p + 1]);
        const float r0 = v[2 * p]     - __builtin_bit_cast(float, (uint)h0 << 16);
        const float r1 = v[2 * p + 1] - __builtin_bit_cast(float, (uint)h1 << 16);
        const ushort l0 = f2bf(r0), l1 = f2bf(r1);
        hw[p] = (uint)h0 | ((uint)h1 << 16);
        lw[p] = (uint)l0 | ((uint)l1 << 16);
    }
    *(uint4*)hiP = make_uint4(hw[0], hw[1], hw[2], hw[3]);
    *(uint4*)loP = make_uint4(lw[0], lw[1], lw[2], lw[3]);
}

__device__ __forceinline__ void ld8(const float* p, float* dst) {
    const float4 a = *(const float4*)p;
    const float4 b = *(const float4*)(p + 4);
    dst[0] = a.x; dst[1] = a.y; dst[2] = a.z; dst[3] = a.w;
    dst[4] = b.x; dst[5] = b.y; dst[6] = b.z; dst[7] = b.w;
}

// Kernel A: 64i x 32j pair tile x 16 t-steps. Split-bf16 3-term MFMA dots.
// 512 blocks, XCD-grouped: all 8 pair-tiles of chunk cz share linearID%8 == cz%8
// -> same XCD L2 -> X/Y slices fetched once per chunk. 2-deep global prefetch ring.
// Full 16-step cumprod history packed as bf16 pairs in regs; epilogue writes
// UNSCALED full-64B t-runs per pair (sector-complete) + fp32 chunk totals P.
__global__ __launch_bounds__(256, 2) void zchunk_kernel(const float* __restrict__ X,
                                                        const float* __restrict__ Y,
                                                        float* __restrict__ out,
                                                        float* __restrict__ P)
{
    __shared__ __align__(16) ushort smXhi[2][64 * 64], smXlo[2][64 * 64];  // 32 KB
    __shared__ __align__(16) ushort smYhi[2][32 * 64], smYlo[2][32 * 64];  // 16 KB

    // swizzled decode: L = (cz&7) + 8*(tile + 8*(cz>>3))
    const int L    = (int)blockIdx.x;          // 0..511
    const int tile = (L >> 3) & 7;             // 0..7
    const int cz   = ((L >> 6) << 3) | (L & 7);// 0..63
    const int i0 = (tile & 1) * 64;
    const int j0 = (tile >> 1) * 32;
    const int t0 = cz * LCH;
    const int tid  = (int)threadIdx.x;
    const int lane = tid & 63, w = tid >> 6, quad = lane >> 4, l15 = lane & 15;

    // staging slots: X rows (tid>>3) and (tid>>3)+32; Y row (tid>>3); k-segment tid&7
    const int srow = tid >> 3;          // 0..31
    const int sseg = tid & 7;
    const float* xp0 = X + (size_t)(i0 + srow)      * TT * DDIM + sseg * 8;
    const float* xp1 = X + (size_t)(i0 + srow + 32) * TT * DDIM + sseg * 8;
    const float* yp  = Y + (size_t)(j0 + srow)      * TT * DDIM + sseg * 8;

    float cx0[8], cx1[8], cy[8];        // slice t0+h values
    float rx0[2][8], rx1[2][8], ry[2][8]; // 2-deep prefetch ring
    {
        const int sa = (t0 == 0) ? 0 : (t0 - 1);
        float pv0[8], pv1[8], pv2[8], d[8];
        // issue all prologue loads first (9 x ld8 in flight)
        ld8(xp0 + (size_t)t0 * DDIM, cx0);
        ld8(xp1 + (size_t)t0 * DDIM, cx1);
        ld8(yp  + (size_t)t0 * DDIM, cy);
        ld8(xp0 + (size_t)sa * DDIM, pv0);
        ld8(xp1 + (size_t)sa * DDIM, pv1);
        ld8(yp  + (size_t)sa * DDIM, pv2);
        ld8(xp0 + (size_t)(t0 + 1) * DDIM, rx0[1]);   // slice t0+1 -> set 1
        ld8(xp1 + (size_t)(t0 + 1) * DDIM, rx1[1]);
        ld8(yp  + (size_t)(t0 + 1) * DDIM, ry[1]);

#pragma unroll
        for (int k = 0; k < 8; ++k) d[k] = cx0[k] - pv0[k];
        cvt_store(&smXhi[0][sidxE(srow, sseg * 8)], &smXlo[0][sidxE(srow, sseg * 8)], d);
#pragma unroll
        for (int k = 0; k < 8; ++k) d[k] = cx1[k] - pv1[k];
        cvt_store(&smXhi[0][sidxE(srow + 32, sseg * 8)], &smXlo[0][sidxE(srow + 32, sseg * 8)], d);
#pragma unroll
        for (int k = 0; k < 8; ++k) d[k] = cy[k] - pv2[k];
        cvt_store(&smYhi[0][sidxE(srow, sseg * 8)], &smYlo[0][sidxE(srow, sseg * 8)], d);
    }

    float cum[2][4];
    uint  histP[2][4][8];               // bf16-packed 16-step history (static-indexed)
#pragma unroll
    for (int s = 0; s < 2; ++s)
#pragma unroll
        for (int r = 0; r < 4; ++r) cum[s][r] = 1.f;

    __syncthreads();

#pragma unroll
    for (int h = 0; h < LCH; ++h) {
        const int cur = h & 1;

        if (h + 2 < LCH) {              // prefetch slice t0+h+2 into ring set h&1
            const size_t u = (size_t)(t0 + h + 2) * DDIM;
            ld8(xp0 + u, rx0[h & 1]); ld8(xp1 + u, rx1[h & 1]); ld8(yp + u, ry[h & 1]);
        }

        // A frags for this wave's 16-row strip (row = w*16 + l15, k = kk*32 + quad*8)
        short8 aHi[2], aLo[2];
#pragma unroll
        for (int kk = 0; kk < 2; ++kk) {
            const int e = sidxE(w * 16 + l15, kk * 32 + quad * 8);
            aHi[kk] = *(const short8*)&smXhi[cur][e];
            aLo[kk] = *(const short8*)&smXlo[cur][e];
        }

#pragma unroll
        for (int sub = 0; sub < 2; ++sub) {
            floatx4 acc = {0.f, 0.f, 0.f, 0.f};
#pragma unroll
            for (int kk = 0; kk < 2; ++kk) {
                const int e = sidxE(sub * 16 + l15, kk * 32 + quad * 8);
                const short8 bHi = *(const short8*)&smYhi[cur][e];
                const short8 bLo = *(const short8*)&smYlo[cur][e];
                acc = __builtin_amdgcn_mfma_f32_16x16x32_bf16(aLo[kk], bHi, acc, 0, 0, 0);
                acc = __builtin_amdgcn_mfma_f32_16x16x32_bf16(aHi[kk], bLo, acc, 0, 0, 0);
                acc = __builtin_amdgcn_mfma_f32_16x16x32_bf16(aHi[kk], bHi, acc, 0, 0, 0);
            }
#pragma unroll
            for (int r = 0; r < 4; ++r) {
                cum[sub][r] *= fmaf(acc[r], DT_INV, 1.f);
                const uint hb = (uint)f2bf(cum[sub][r]);
                if ((h & 1) == 0) histP[sub][r][h >> 1] = hb;
                else              histP[sub][r][h >> 1] |= (hb << 16);
            }
        }

        if (h + 1 < LCH) {              // stage next step's diffs into other buffer
            const int nsel = (h + 1) & 1;   // ring set holding slice t0+h+1
            float d[8];
#pragma unroll
            for (int k = 0; k < 8; ++k) d[k] = rx0[nsel][k] - cx0[k];
            cvt_store(&smXhi[cur ^ 1][sidxE(srow, sseg * 8)], &smXlo[cur ^ 1][sidxE(srow, sseg * 8)], d);
#pragma unroll
            for (int k = 0; k < 8; ++k) d[k] = rx1[nsel][k] - cx1[k];
            cvt_store(&smXhi[cur ^ 1][sidxE(srow + 32, sseg * 8)], &smXlo[cur ^ 1][sidxE(srow + 32, sseg * 8)], d);
#pragma unroll
            for (int k = 0; k < 8; ++k) d[k] = ry[nsel][k] - cy[k];
            cvt_store(&smYhi[cur ^ 1][sidxE(srow, sseg * 8)], &smYlo[cur ^ 1][sidxE(srow, sseg * 8)], d);
#pragma unroll
            for (int k = 0; k < 8; ++k) { cx0[k] = rx0[nsel][k]; cx1[k] = rx1[nsel][k]; cy[k] = ry[nsel][k]; }
            __syncthreads();
        }
    }

    // Epilogue: fp32 chunk totals + UNSCALED bf16 history as full-64B runs.
#pragma unroll
    for (int sub = 0; sub < 2; ++sub)
#pragma unroll
        for (int r = 0; r < 4; ++r) {
            const int pair = (i0 + w * 16 + quad * 4 + r) * BX + (j0 + sub * 16 + l15);
            P[(size_t)cz * NPAIR + pair] = cum[sub][r];
            float* o = out + (size_t)pair * TT + t0;
#pragma unroll
            for (int q = 0; q < 4; ++q) {
                const uint u0 = histP[sub][r][2 * q];
                const uint u1 = histP[sub][r][2 * q + 1];
                *(float4*)(o + q * 4) = make_float4(
                    __builtin_bit_cast(float, u0 << 16),
                    __builtin_bit_cast(float, u0 & 0xffff0000u),
                    __builtin_bit_cast(float, u1 << 16),
                    __builtin_bit_cast(float, u1 & 0xffff0000u));
            }
        }
}

// Kernel B: fused scan+scale. Block = 16 consecutive pairs.
// Phase A: 16 threads compute the 64-chunk exclusive prefix products -> LDS.
// Phase B: 256 threads RMW-scale out rows in coalesced 256B segments.
__global__ __launch_bounds__(256) void scanscale_kernel(float* __restrict__ out,
                                                        const float* __restrict__ P)
{
    __shared__ float pf[16][NCH];       // 4 KB
    const int p0  = (int)blockIdx.x * 16;
    const int tid = (int)threadIdx.x;

    if (tid < 16) {
        const int p = p0 + tid;
        float run = 1.f;
#pragma unroll 4
        for (int c = 0; c < NCH; ++c) {
            pf[tid][c] = run;
            run *= P[(size_t)c * NPAIR + p];
        }
    }
    __syncthreads();

    const int pp  = tid >> 4;           // 0..15 pair within block
    const int col = tid & 15;           // 0..15
    float* row = out + (size_t)(p0 + pp) * TT;
#pragma unroll
    for (int seg = 0; seg < 16; ++seg) {
        const int t = seg * 64 + col * 4;
        const float f = pf[pp][t >> 4];
        float4 v = *(float4*)(row + t);
        v.x *= f; v.y *= f; v.z *= f; v.w *= f;
        *(float4*)(row + t) = v;
    }
}

extern "C" void kernel_launch(void* const* d_in, const int* in_sizes, int n_in,
                              void* d_out, int out_size, void* d_ws, size_t ws_size,
                              hipStream_t stream)
{
    const float* X = (const float*)d_in[0];
    const float* Y = (const float*)d_in[1];
    float* out = (float*)d_out;
    float* P   = (float*)d_ws;          // NCH*NPAIR*4 = 4 MB

    zchunk_kernel<<<dim3(512), 256, 0, stream>>>(X, Y, out, P);
    scanscale_kernel<<<dim3(NPAIR / 16), 256, 0, stream>>>(out, P);
}

// Round 4
// 162.877 us; speedup vs baseline: 1.3187x; 1.1488x over previous
//
#include <hip/hip_runtime.h>

typedef __attribute__((ext_vector_type(8))) short short8;   // 8 bf16 (4 VGPRs)
typedef __attribute__((ext_vector_type(4))) float floatx4;  // MFMA C/D

// (B,T,D) = (128,1024,64) fp32. out[i][j][t] = prod_{s<=t}(1 + <dX(s-1),dY(s-1)>/dt)
constexpr int BX    = 128;
constexpr int TT    = 1024;
constexpr int DDIM  = 64;
constexpr int NPAIR = BX * BX;
constexpr int LCH   = 16;              // t-steps per block
constexpr int NCH   = TT / LCH;        // 64
constexpr float DT_INV = 1023.0f;

// LDS element index for bf16 rows of 64 with XOR-segment swizzle (16B segments).
__device__ __forceinline__ int sidxE(int row, int k) {
    return row * 64 + ((((k >> 3) ^ (row & 7)) << 3) | (k & 7));
}

__device__ __forceinline__ ushort f2bf(float f) {           // round-to-nearest-even bf16
    uint u = __builtin_bit_cast(uint, f);
    u += 0x7fffu + ((u >> 16) & 1u);
    return (ushort)(u >> 16);
}

// 8 floats -> hi/lo bf16 split, two 16B LDS stores.
__device__ __forceinline__ void cvt_store(ushort* hiP, ushort* loP, const float* v) {
    uint hw[4], lw[4];
#pragma unroll
    for (int p = 0; p < 4; ++p) {
        const ushort h0 = f2bf(v[2 * p]), h1 = f2bf(v[2 * p + 1]);
        const float r0 = v[2 * p]     - __builtin_bit_cast(float, (uint)h0 << 16);
        const float r1 = v[2 * p + 1] - __builtin_bit_cast(float, (uint)h1 << 16);
        const ushort l0 = f2bf(r0), l1 = f2bf(r1);
        hw[p] = (uint)h0 | ((uint)h1 << 16);
        lw[p] = (uint)l0 | ((uint)l1 << 16);
    }
    *(uint4*)hiP = make_uint4(hw[0], hw[1], hw[2], hw[3]);
    *(uint4*)loP = make_uint4(lw[0], lw[1], lw[2], lw[3]);
}

__device__ __forceinline__ void ld8(const float* p, float* dst) {
    const float4 a = *(const float4*)p;
    const float4 b = *(const float4*)(p + 4);
    dst[0] = a.x; dst[1] = a.y; dst[2] = a.z; dst[3] = a.w;
    dst[4] = b.x; dst[5] = b.y; dst[6] = b.z; dst[7] = b.w;
}

// Kernel A: 64i x 32j pair tile x 16 t-steps. Split-bf16 3-term MFMA dots.
// 512 blocks XCD-grouped (linearID%8 == cz%8 -> same-XCD L2 sharing of X/Y slices).
// WP=1: epilogue writes unscaled history to W[cz][pair][16] -> 1KB contiguous
//       full-line stores per (sub,r). WP=0: legacy direct [pair][t] 64B stores.
template<int WP>
__global__ __launch_bounds__(256, 2) void zchunk_kernel(const float* __restrict__ X,
                                                        const float* __restrict__ Y,
                                                        float* __restrict__ dst,
                                                        float* __restrict__ P)
{
    __shared__ __align__(16) ushort smXhi[2][64 * 64], smXlo[2][64 * 64];  // 32 KB
    __shared__ __align__(16) ushort smYhi[2][32 * 64], smYlo[2][32 * 64];  // 16 KB

    // swizzled decode: L = (cz&7) + 8*(tile + 8*(cz>>3))
    const int L    = (int)blockIdx.x;          // 0..511
    const int tile = (L >> 3) & 7;             // 0..7
    const int cz   = ((L >> 6) << 3) | (L & 7);// 0..63
    const int i0 = (tile & 1) * 64;
    const int j0 = (tile >> 1) * 32;
    const int t0 = cz * LCH;
    const int tid  = (int)threadIdx.x;
    const int lane = tid & 63, w = tid >> 6, quad = lane >> 4, l15 = lane & 15;

    const int srow = tid >> 3;          // 0..31
    const int sseg = tid & 7;
    const float* xp0 = X + (size_t)(i0 + srow)      * TT * DDIM + sseg * 8;
    const float* xp1 = X + (size_t)(i0 + srow + 32) * TT * DDIM + sseg * 8;
    const float* yp  = Y + (size_t)(j0 + srow)      * TT * DDIM + sseg * 8;

    float cx0[8], cx1[8], cy[8];          // slice t0+h values
    float rx0[2][8], rx1[2][8], ry[2][8]; // 2-deep prefetch ring
    {
        const int sa = (t0 == 0) ? 0 : (t0 - 1);
        float pv0[8], pv1[8], pv2[8], d[8];
        ld8(xp0 + (size_t)t0 * DDIM, cx0);
        ld8(xp1 + (size_t)t0 * DDIM, cx1);
        ld8(yp  + (size_t)t0 * DDIM, cy);
        ld8(xp0 + (size_t)sa * DDIM, pv0);
        ld8(xp1 + (size_t)sa * DDIM, pv1);
        ld8(yp  + (size_t)sa * DDIM, pv2);
        ld8(xp0 + (size_t)(t0 + 1) * DDIM, rx0[1]);   // slice t0+1 -> set 1
        ld8(xp1 + (size_t)(t0 + 1) * DDIM, rx1[1]);
        ld8(yp  + (size_t)(t0 + 1) * DDIM, ry[1]);

#pragma unroll
        for (int k = 0; k < 8; ++k) d[k] = cx0[k] - pv0[k];
        cvt_store(&smXhi[0][sidxE(srow, sseg * 8)], &smXlo[0][sidxE(srow, sseg * 8)], d);
#pragma unroll
        for (int k = 0; k < 8; ++k) d[k] = cx1[k] - pv1[k];
        cvt_store(&smXhi[0][sidxE(srow + 32, sseg * 8)], &smXlo[0][sidxE(srow + 32, sseg * 8)], d);
#pragma unroll
        for (int k = 0; k < 8; ++k) d[k] = cy[k] - pv2[k];
        cvt_store(&smYhi[0][sidxE(srow, sseg * 8)], &smYlo[0][sidxE(srow, sseg * 8)], d);
    }

    float cum[2][4];
    uint  histP[2][4][8];               // bf16-packed 16-step history (static-indexed)
#pragma unroll
    for (int s = 0; s < 2; ++s)
#pragma unroll
        for (int r = 0; r < 4; ++r) cum[s][r] = 1.f;

    __syncthreads();

#pragma unroll
    for (int h = 0; h < LCH; ++h) {
        const int cur = h & 1;

        if (h + 2 < LCH) {              // prefetch slice t0+h+2 into ring set h&1
            const size_t u = (size_t)(t0 + h + 2) * DDIM;
            ld8(xp0 + u, rx0[h & 1]); ld8(xp1 + u, rx1[h & 1]); ld8(yp + u, ry[h & 1]);
        }

        short8 aHi[2], aLo[2];
#pragma unroll
        for (int kk = 0; kk < 2; ++kk) {
            const int e = sidxE(w * 16 + l15, kk * 32 + quad * 8);
            aHi[kk] = *(const short8*)&smXhi[cur][e];
            aLo[kk] = *(const short8*)&smXlo[cur][e];
        }

#pragma unroll
        for (int sub = 0; sub < 2; ++sub) {
            floatx4 acc = {0.f, 0.f, 0.f, 0.f};
#pragma unroll
            for (int kk = 0; kk < 2; ++kk) {
                const int e = sidxE(sub * 16 + l15, kk * 32 + quad * 8);
                const short8 bHi = *(const short8*)&smYhi[cur][e];
                const short8 bLo = *(const short8*)&smYlo[cur][e];
                acc = __builtin_amdgcn_mfma_f32_16x16x32_bf16(aLo[kk], bHi, acc, 0, 0, 0);
                acc = __builtin_amdgcn_mfma_f32_16x16x32_bf16(aHi[kk], bLo, acc, 0, 0, 0);
                acc = __builtin_amdgcn_mfma_f32_16x16x32_bf16(aHi[kk], bHi, acc, 0, 0, 0);
            }
#pragma unroll
            for (int r = 0; r < 4; ++r) {
                cum[sub][r] *= fmaf(acc[r], DT_INV, 1.f);
                const uint hb = (uint)f2bf(cum[sub][r]);
                if ((h & 1) == 0) histP[sub][r][h >> 1] = hb;
                else              histP[sub][r][h >> 1] |= (hb << 16);
            }
        }

        if (h + 1 < LCH) {              // stage next step's diffs into other buffer
            const int nsel = (h + 1) & 1;
            float d[8];
#pragma unroll
            for (int k = 0; k < 8; ++k) d[k] = rx0[nsel][k] - cx0[k];
            cvt_store(&smXhi[cur ^ 1][sidxE(srow, sseg * 8)], &smXlo[cur ^ 1][sidxE(srow, sseg * 8)], d);
#pragma unroll
            for (int k = 0; k < 8; ++k) d[k] = rx1[nsel][k] - cx1[k];
            cvt_store(&smXhi[cur ^ 1][sidxE(srow + 32, sseg * 8)], &smXlo[cur ^ 1][sidxE(srow + 32, sseg * 8)], d);
#pragma unroll
            for (int k = 0; k < 8; ++k) d[k] = ry[nsel][k] - cy[k];
            cvt_store(&smYhi[cur ^ 1][sidxE(srow, sseg * 8)], &smYlo[cur ^ 1][sidxE(srow, sseg * 8)], d);
#pragma unroll
            for (int k = 0; k < 8; ++k) { cx0[k] = rx0[nsel][k]; cx1[k] = rx1[nsel][k]; cy[k] = ry[nsel][k]; }
            __syncthreads();
        }
    }

    // Epilogue: fp32 chunk totals + UNSCALED bf16 history.
#pragma unroll
    for (int sub = 0; sub < 2; ++sub)
#pragma unroll
        for (int r = 0; r < 4; ++r) {
            const int pair = (i0 + w * 16 + quad * 4 + r) * BX + (j0 + sub * 16 + l15);
            P[(size_t)cz * NPAIR + pair] = cum[sub][r];
            float* o = WP ? (dst + ((size_t)cz * NPAIR + pair) * LCH)   // W[cz][pair][16]
                          : (dst + (size_t)pair * TT + t0);             // out[pair][t]
#pragma unroll
            for (int q = 0; q < 4; ++q) {
                const uint u0 = histP[sub][r][2 * q];
                const uint u1 = histP[sub][r][2 * q + 1];
                *(float4*)(o + q * 4) = make_float4(
                    __builtin_bit_cast(float, u0 << 16),
                    __builtin_bit_cast(float, u0 & 0xffff0000u),
                    __builtin_bit_cast(float, u1 << 16),
                    __builtin_bit_cast(float, u1 & 0xffff0000u));
            }
        }
}

// Kernel B (W-path): block = 64 consecutive pairs, 256 threads.
// Phase 1: fully-parallel exclusive chunk-prefix (per-thread 16-chunk local prefix
//          + LDS cross-segment combine) -> pf[64][65] in LDS.
// Phase 2: 64 passes; pass r writes pair p0+r's FULL 4KB t-row contiguously,
//          gathering from W[c][pair][16] and scaling by pf[c][r].
__global__ __launch_bounds__(256) void scanscale_w(float* __restrict__ out,
                                                   const float* __restrict__ W,
                                                   const float* __restrict__ P)
{
    __shared__ float pf[NCH * 65];      // padded stride 65 -> conflict-free
    __shared__ float tot[4][64];

    const int p0  = (int)blockIdx.x * 64;
    const int tid = (int)threadIdx.x;
    const int p   = tid & 63;           // pair offset within block
    const int cs  = tid >> 6;           // chunk segment 0..3 (16 chunks each)

    float v[16], e[16];
#pragma unroll
    for (int k = 0; k < 16; ++k)
        v[k] = P[(size_t)(cs * 16 + k) * NPAIR + p0 + p];
    e[0] = 1.f;
#pragma unroll
    for (int k = 1; k < 16; ++k) e[k] = e[k - 1] * v[k - 1];
    tot[cs][p] = e[15] * v[15];
    __syncthreads();

    float base = 1.f;
#pragma unroll
    for (int q = 0; q < 3; ++q)
        if (q < cs) base *= tot[q][p];
#pragma unroll
    for (int k = 0; k < 16; ++k)
        pf[(cs * 16 + k) * 65 + p] = base * e[k];
    __syncthreads();

    const int c  = tid >> 2;            // chunk for phase 2 (t = tid*4)
    const int tq = tid & 3;
#pragma unroll 2
    for (int r = 0; r < 64; ++r) {
        const int pair = p0 + r;
        const float f = pf[c * 65 + r];
        const float4 w4 = *(const float4*)(W + ((size_t)c * NPAIR + pair) * LCH + tq * 4);
        *(float4*)(out + (size_t)pair * TT + tid * 4) =
            make_float4(w4.x * f, w4.y * f, w4.z * f, w4.w * f);
    }
}

// Legacy fallback kernel B: scan+RMW-scale of out in place.
__global__ __launch_bounds__(256) void scanscale_kernel(float* __restrict__ out,
                                                        const float* __restrict__ P)
{
    __shared__ float pf[16][NCH];       // 4 KB
    const int p0  = (int)blockIdx.x * 16;
    const int tid = (int)threadIdx.x;

    if (tid < 16) {
        const int p = p0 + tid;
        float run = 1.f;
#pragma unroll 4
        for (int c = 0; c < NCH; ++c) {
            pf[tid][c] = run;
            run *= P[(size_t)c * NPAIR + p];
        }
    }
    __syncthreads();

    const int pp  = tid >> 4;
    const int col = tid & 15;
    float* row = out + (size_t)(p0 + pp) * TT;
#pragma unroll
    for (int seg = 0; seg < 16; ++seg) {
        const int t = seg * 64 + col * 4;
        const float f = pf[pp][t >> 4];
        float4 v = *(float4*)(row + t);
        v.x *= f; v.y *= f; v.z *= f; v.w *= f;
        *(float4*)(row + t) = v;
    }
}

extern "C" void kernel_launch(void* const* d_in, const int* in_sizes, int n_in,
                              void* d_out, int out_size, void* d_ws, size_t ws_size,
                              hipStream_t stream)
{
    const float* X = (const float*)d_in[0];
    const float* Y = (const float*)d_in[1];
    float* out = (float*)d_out;
    float* P   = (float*)d_ws;                          // 4 MB
    float* W   = (float*)d_ws + (size_t)NCH * NPAIR;    // 64 MB (W[cz][pair][16])

    const size_t need = ((size_t)NCH * NPAIR + (size_t)NPAIR * TT) * sizeof(float);
    if (ws_size >= need) {
        zchunk_kernel<1><<<dim3(512), 256, 0, stream>>>(X, Y, W, P);
        scanscale_w<<<dim3(NPAIR / 64), 256, 0, stream>>>(out, W, P);
    } else {
        zchunk_kernel<0><<<dim3(512), 256, 0, stream>>>(X, Y, out, P);
        scanscale_kernel<<<dim3(NPAIR / 16), 256, 0, stream>>>(out, P);
    }
}

// Round 5
// 156.935 us; speedup vs baseline: 1.3687x; 1.0379x over previous
//
#include <hip/hip_runtime.h>

typedef __attribute__((ext_vector_type(8))) short short8;   // 8 bf16 (4 VGPRs)
typedef __attribute__((ext_vector_type(4))) float floatx4;  // MFMA C/D

// (B,T,D) = (128,1024,64) fp32. out[i][j][t] = prod_{s<=t}(1 + <dX(s-1),dY(s-1)>/dt)
constexpr int BX    = 128;
constexpr int TT    = 1024;
constexpr int DDIM  = 64;
constexpr int NPAIR = BX * BX;
constexpr int LCH   = 16;              // t-steps per block
constexpr int NCH   = TT / LCH;        // 64
constexpr float DT_INV = 1023.0f;

// LDS element index for bf16 rows of 64 with XOR-segment swizzle (16B segments).
__device__ __forceinline__ int sidxE(int row, int k) {
    return row * 64 + ((((k >> 3) ^ (row & 7)) << 3) | (k & 7));
}

__device__ __forceinline__ ushort f2bf(float f) {           // round-to-nearest-even bf16
    uint u = __builtin_bit_cast(uint, f);
    u += 0x7fffu + ((u >> 16) & 1u);
    return (ushort)(u >> 16);
}

// 8 floats -> hi/lo bf16 split, two 16B LDS stores.
__device__ __forceinline__ void cvt_store(ushort* hiP, ushort* loP, const float* v) {
    uint hw[4], lw[4];
#pragma unroll
    for (int p = 0; p < 4; ++p) {
        const ushort h0 = f2bf(v[2 * p]), h1 = f2bf(v[2 * p + 1]);
        const float r0 = v[2 * p]     - __builtin_bit_cast(float, (uint)h0 << 16);
        const float r1 = v[2 * p + 1] - __builtin_bit_cast(float, (uint)h1 << 16);
        const ushort l0 = f2bf(r0), l1 = f2bf(r1);
        hw[p] = (uint)h0 | ((uint)h1 << 16);
        lw[p] = (uint)l0 | ((uint)l1 << 16);
    }
    *(uint4*)hiP = make_uint4(hw[0], hw[1], hw[2], hw[3]);
    *(uint4*)loP = make_uint4(lw[0], lw[1], lw[2], lw[3]);
}

__device__ __forceinline__ void ld8(const float* p, float* dst) {
    const float4 a = *(const float4*)p;
    const float4 b = *(const float4*)(p + 4);
    dst[0] = a.x; dst[1] = a.y; dst[2] = a.z; dst[3] = a.w;
    dst[4] = b.x; dst[5] = b.y; dst[6] = b.z; dst[7] = b.w;
}

// Kernel A: 64i x 32j pair tile x 16 t-steps. Split-bf16 3-term MFMA dots.
// 512 blocks XCD-grouped (linearID%8 == cz%8 -> same-XCD L2 sharing of X/Y slices).
// WP=1: epilogue writes unscaled history to W[cz][pair][16] -> 1KB contiguous
//       full-line stores per (sub,r). WP=0: legacy direct [pair][t] 64B stores.
template<int WP>
__global__ __launch_bounds__(256, 2) void zchunk_kernel(const float* __restrict__ X,
                                                        const float* __restrict__ Y,
                                                        float* __restrict__ dst,
                                                        float* __restrict__ P)
{
    __shared__ __align__(16) ushort smXhi[2][64 * 64], smXlo[2][64 * 64];  // 32 KB
    __shared__ __align__(16) ushort smYhi[2][32 * 64], smYlo[2][32 * 64];  // 16 KB

    // swizzled decode: L = (cz&7) + 8*(tile + 8*(cz>>3))
    const int L    = (int)blockIdx.x;          // 0..511
    const int tile = (L >> 3) & 7;             // 0..7
    const int cz   = ((L >> 6) << 3) | (L & 7);// 0..63
    const int i0 = (tile & 1) * 64;
    const int j0 = (tile >> 1) * 32;
    const int t0 = cz * LCH;
    const int tid  = (int)threadIdx.x;
    const int lane = tid & 63, w = tid >> 6, quad = lane >> 4, l15 = lane & 15;

    const int srow = tid >> 3;          // 0..31
    const int sseg = tid & 7;
    const float* xp0 = X + (size_t)(i0 + srow)      * TT * DDIM + sseg * 8;
    const float* xp1 = X + (size_t)(i0 + srow + 32) * TT * DDIM + sseg * 8;
    const float* yp  = Y + (size_t)(j0 + srow)      * TT * DDIM + sseg * 8;

    float cx0[8], cx1[8], cy[8];          // slice t0+h values
    float rx0[2][8], rx1[2][8], ry[2][8]; // 2-deep prefetch ring
    {
        const int sa = (t0 == 0) ? 0 : (t0 - 1);
        float pv0[8], pv1[8], pv2[8], d[8];
        ld8(xp0 + (size_t)t0 * DDIM, cx0);
        ld8(xp1 + (size_t)t0 * DDIM, cx1);
        ld8(yp  + (size_t)t0 * DDIM, cy);
        ld8(xp0 + (size_t)sa * DDIM, pv0);
        ld8(xp1 + (size_t)sa * DDIM, pv1);
        ld8(yp  + (size_t)sa * DDIM, pv2);
        ld8(xp0 + (size_t)(t0 + 1) * DDIM, rx0[1]);   // slice t0+1 -> set 1
        ld8(xp1 + (size_t)(t0 + 1) * DDIM, rx1[1]);
        ld8(yp  + (size_t)(t0 + 1) * DDIM, ry[1]);

#pragma unroll
        for (int k = 0; k < 8; ++k) d[k] = cx0[k] - pv0[k];
        cvt_store(&smXhi[0][sidxE(srow, sseg * 8)], &smXlo[0][sidxE(srow, sseg * 8)], d);
#pragma unroll
        for (int k = 0; k < 8; ++k) d[k] = cx1[k] - pv1[k];
        cvt_store(&smXhi[0][sidxE(srow + 32, sseg * 8)], &smXlo[0][sidxE(srow + 32, sseg * 8)], d);
#pragma unroll
        for (int k = 0; k < 8; ++k) d[k] = cy[k] - pv2[k];
        cvt_store(&smYhi[0][sidxE(srow, sseg * 8)], &smYlo[0][sidxE(srow, sseg * 8)], d);
    }

    float cum[2][4];
    uint  histP[2][4][8];               // bf16-packed 16-step history (static-indexed)
#pragma unroll
    for (int s = 0; s < 2; ++s)
#pragma unroll
        for (int r = 0; r < 4; ++r) cum[s][r] = 1.f;

    __syncthreads();

#pragma unroll
    for (int h = 0; h < LCH; ++h) {
        const int cur = h & 1;

        if (h + 2 < LCH) {              // prefetch slice t0+h+2 into ring set h&1
            const size_t u = (size_t)(t0 + h + 2) * DDIM;
            ld8(xp0 + u, rx0[h & 1]); ld8(xp1 + u, rx1[h & 1]); ld8(yp + u, ry[h & 1]);
        }

        short8 aHi[2], aLo[2];
#pragma unroll
        for (int kk = 0; kk < 2; ++kk) {
            const int e = sidxE(w * 16 + l15, kk * 32 + quad * 8);
            aHi[kk] = *(const short8*)&smXhi[cur][e];
            aLo[kk] = *(const short8*)&smXlo[cur][e];
        }

#pragma unroll
        for (int sub = 0; sub < 2; ++sub) {
            floatx4 acc = {0.f, 0.f, 0.f, 0.f};
#pragma unroll
            for (int kk = 0; kk < 2; ++kk) {
                const int e = sidxE(sub * 16 + l15, kk * 32 + quad * 8);
                const short8 bHi = *(const short8*)&smYhi[cur][e];
                const short8 bLo = *(const short8*)&smYlo[cur][e];
                acc = __builtin_amdgcn_mfma_f32_16x16x32_bf16(aLo[kk], bHi, acc, 0, 0, 0);
                acc = __builtin_amdgcn_mfma_f32_16x16x32_bf16(aHi[kk], bLo, acc, 0, 0, 0);
                acc = __builtin_amdgcn_mfma_f32_16x16x32_bf16(aHi[kk], bHi, acc, 0, 0, 0);
            }
#pragma unroll
            for (int r = 0; r < 4; ++r) {
                cum[sub][r] *= fmaf(acc[r], DT_INV, 1.f);
                const uint hb = (uint)f2bf(cum[sub][r]);
                if ((h & 1) == 0) histP[sub][r][h >> 1] = hb;
                else              histP[sub][r][h >> 1] |= (hb << 16);
            }
        }

        if (h + 1 < LCH) {              // stage next step's diffs into other buffer
            const int nsel = (h + 1) & 1;
            float d[8];
#pragma unroll
            for (int k = 0; k < 8; ++k) d[k] = rx0[nsel][k] - cx0[k];
            cvt_store(&smXhi[cur ^ 1][sidxE(srow, sseg * 8)], &smXlo[cur ^ 1][sidxE(srow, sseg * 8)], d);
#pragma unroll
            for (int k = 0; k < 8; ++k) d[k] = rx1[nsel][k] - cx1[k];
            cvt_store(&smXhi[cur ^ 1][sidxE(srow + 32, sseg * 8)], &smXlo[cur ^ 1][sidxE(srow + 32, sseg * 8)], d);
#pragma unroll
            for (int k = 0; k < 8; ++k) d[k] = ry[nsel][k] - cy[k];
            cvt_store(&smYhi[cur ^ 1][sidxE(srow, sseg * 8)], &smYlo[cur ^ 1][sidxE(srow, sseg * 8)], d);
#pragma unroll
            for (int k = 0; k < 8; ++k) { cx0[k] = rx0[nsel][k]; cx1[k] = rx1[nsel][k]; cy[k] = ry[nsel][k]; }
            __syncthreads();
        }
    }

    // Epilogue: fp32 chunk totals + UNSCALED bf16 history.
#pragma unroll
    for (int sub = 0; sub < 2; ++sub)
#pragma unroll
        for (int r = 0; r < 4; ++r) {
            const int pair = (i0 + w * 16 + quad * 4 + r) * BX + (j0 + sub * 16 + l15);
            P[(size_t)cz * NPAIR + pair] = cum[sub][r];
            float* o = WP ? (dst + ((size_t)cz * NPAIR + pair) * LCH)   // W[cz][pair][16]
                          : (dst + (size_t)pair * TT + t0);             // out[pair][t]
#pragma unroll
            for (int q = 0; q < 4; ++q) {
                const uint u0 = histP[sub][r][2 * q];
                const uint u1 = histP[sub][r][2 * q + 1];
                *(float4*)(o + q * 4) = make_float4(
                    __builtin_bit_cast(float, u0 << 16),
                    __builtin_bit_cast(float, u0 & 0xffff0000u),
                    __builtin_bit_cast(float, u1 << 16),
                    __builtin_bit_cast(float, u1 & 0xffff0000u));
            }
        }
}

// Kernel B (W-path) v2: block = 16 pairs, 1024 blocks = 4/CU (4 waves/SIMD).
// Phase 1: parallel exclusive chunk-prefix: 16 segs x 16 pairs, 4-chunk local
//          prefix per thread + LDS cross-segment combine -> pf[64][pair].
// Phase 2: 16 passes batched x4 (4 loads in flight); pass r writes pair p0+r's
//          full 4KB t-row contiguously from W[c][pair][16] * pf[c][r].
__global__ __launch_bounds__(256) void scanscale_w(float* __restrict__ out,
                                                   const float* __restrict__ W,
                                                   const float* __restrict__ P)
{
    __shared__ float pf[NCH][17];       // [chunk][pair] padded
    __shared__ float tot[16][17];       // [seg][pair]

    const int p0  = (int)blockIdx.x * 16;
    const int tid = (int)threadIdx.x;
    const int p   = tid & 15;           // pair 0..15
    const int seg = tid >> 4;           // 0..15 (chunks seg*4..+3)

    float v[4], e[4];
#pragma unroll
    for (int k = 0; k < 4; ++k)
        v[k] = P[(size_t)(seg * 4 + k) * NPAIR + p0 + p];
    e[0] = 1.f;
#pragma unroll
    for (int k = 1; k < 4; ++k) e[k] = e[k - 1] * v[k - 1];
    tot[seg][p] = e[3] * v[3];
    __syncthreads();

    float base = 1.f;
#pragma unroll
    for (int q = 0; q < 15; ++q)
        if (q < seg) base *= tot[q][p];
#pragma unroll
    for (int k = 0; k < 4; ++k)
        pf[seg * 4 + k][p] = base * e[k];
    __syncthreads();

    const int c  = tid >> 2;            // chunk (t = tid*4 = c*16 + tq*4)
    const int tq = tid & 3;
#pragma unroll
    for (int rb = 0; rb < 4; ++rb) {    // 4 batches x 4 pairs
        float4 w4[4];
        float  f[4];
#pragma unroll
        for (int u = 0; u < 4; ++u) {   // issue 4 independent loads first
            const int r = rb * 4 + u;
            f[u]  = pf[c][r];
            w4[u] = *(const float4*)(W + ((size_t)c * NPAIR + p0 + r) * LCH + tq * 4);
        }
#pragma unroll
        for (int u = 0; u < 4; ++u) {
            const int r = rb * 4 + u;
            *(float4*)(out + (size_t)(p0 + r) * TT + tid * 4) =
                make_float4(w4[u].x * f[u], w4[u].y * f[u],
                            w4[u].z * f[u], w4[u].w * f[u]);
        }
    }
}

// Legacy fallback kernel B: scan+RMW-scale of out in place.
__global__ __launch_bounds__(256) void scanscale_kernel(float* __restrict__ out,
                                                        const float* __restrict__ P)
{
    __shared__ float pf[16][NCH];       // 4 KB
    const int p0  = (int)blockIdx.x * 16;
    const int tid = (int)threadIdx.x;

    if (tid < 16) {
        const int p = p0 + tid;
        float run = 1.f;
#pragma unroll 4
        for (int c = 0; c < NCH; ++c) {
            pf[tid][c] = run;
            run *= P[(size_t)c * NPAIR + p];
        }
    }
    __syncthreads();

    const int pp  = tid >> 4;
    const int col = tid & 15;
    float* row = out + (size_t)(p0 + pp) * TT;
#pragma unroll
    for (int seg = 0; seg < 16; ++seg) {
        const int t = seg * 64 + col * 4;
        const float f = pf[pp][t >> 4];
        float4 v = *(float4*)(row + t);
        v.x *= f; v.y *= f; v.z *= f; v.w *= f;
        *(float4*)(row + t) = v;
    }
}

extern "C" void kernel_launch(void* const* d_in, const int* in_sizes, int n_in,
                              void* d_out, int out_size, void* d_ws, size_t ws_size,
                              hipStream_t stream)
{
    const float* X = (const float*)d_in[0];
    const float* Y = (const float*)d_in[1];
    float* out = (float*)d_out;
    float* P   = (float*)d_ws;                          // 4 MB
    float* W   = (float*)d_ws + (size_t)NCH * NPAIR;    // 64 MB (W[cz][pair][16])

    const size_t need = ((size_t)NCH * NPAIR + (size_t)NPAIR * TT) * sizeof(float);
    if (ws_size >= need) {
        zchunk_kernel<1><<<dim3(512), 256, 0, stream>>>(X, Y, W, P);
        scanscale_w<<<dim3(NPAIR / 16), 256, 0, stream>>>(out, W, P);
    } else {
        zchunk_kernel<0><<<dim3(512), 256, 0, stream>>>(X, Y, out, P);
        scanscale_kernel<<<dim3(NPAIR / 16), 256, 0, stream>>>(out, P);
    }
}